// Round 4
// baseline (111.803 us; speedup 1.0000x reference)
//
#include <hip/hip_runtime.h>

// GenomeNet: B=4096, N_IN=W=N_OUT=1024, L=8 hidden, D=16 fan-in.
// R10: R9 structure (TB=16, lane-pair-split 32B rows, fmaf inner loop,
// one-pass-ahead weight prefetch) + CROSS-PASS software pipelining.
//   R9 post-mortem: LDS pipe only ~71% busy, VALU ~52%, neither saturated.
//   Residual = pipeline drain at every pass boundary: gather ends with 8
//   loads consumed/none issued, then a VALU-only tanh tail, then the next
//   pass restarts from empty (20 drains, all waves barrier-locked into the
//   same phase). Fix: while pass-0's second-half FMAs run, issue pass-1's
//   first 8 ds_reads, so the LDS pipe stays fed through the tanh-0 tail.
//   Same for the two output passes. Arithmetic order per node unchanged.

#define TB       16
#define W_NODES  1024
#define LAYERS   8
#define ROW_H    16                    // halfs per node row (32 B)
#define BUF_H    (W_NODES * ROW_H)     // 16384 halfs = 32 KB

typedef _Float16 h8 __attribute__((ext_vector_type(8)));

__device__ __forceinline__ float fast_tanh(float x) {
    // tanh(x) = 1 - 2/(e^{2x}+1)
    float a = __builtin_amdgcn_exp2f(x * 2.8853900817779268f);
    return 1.0f - 2.0f * __builtin_amdgcn_rcpf(a + 1.0f);
}

// Per-node edge data: 16 src indices + 16 weights, packed in regs.
struct SW { int4 s[4]; float4 w[4]; };

__device__ __forceinline__ void load_sw(const int4* __restrict__ sp,
                                        const float4* __restrict__ wp,
                                        SW& d) {
    #pragma unroll
    for (int q = 0; q < 4; ++q) { d.s[q] = sp[q]; d.w[q] = wp[q]; }
}

__device__ __forceinline__ void unpack_sw(const SW& d,
                                          int* __restrict__ si,
                                          float* __restrict__ wi) {
    #pragma unroll
    for (int q = 0; q < 4; ++q) {
        si[4*q+0] = d.s[q].x; si[4*q+1] = d.s[q].y;
        si[4*q+2] = d.s[q].z; si[4*q+3] = d.s[q].w;
        wi[4*q+0] = d.w[q].x; wi[4*q+1] = d.w[q].y;
        wi[4*q+2] = d.w[q].z; wi[4*q+3] = d.w[q].w;
    }
}

__global__ __launch_bounds__(1024, 4) void genome_net(
    const float* __restrict__ x,
    const int*   __restrict__ src_hidden,
    const float* __restrict__ w_hidden,
    const int*   __restrict__ src_out,
    const float* __restrict__ w_out,
    float*       __restrict__ out)
{
    extern __shared__ _Float16 lds[];
    _Float16* bufA = lds;              // [1024 nodes][16 batch] fp16, 32 KB
    _Float16* bufB = lds + BUF_H;

    const int t   = threadIdx.x;
    const int pr  = t >> 1;            // pair index 0..511
    const int hf  = t & 1;             // which 16 B half of the row
    const int hfo = hf << 3;           // half offset in halfs
    const int b0  = blockIdx.x * TB;
    const int bb  = b0 + hfo;          // this thread's 8-batch base

    const int n0 = pr;                 // pass-0 node
    const int n1 = 512 + pr;           // pass-1 node

    const int4*   shp = (const int4*)src_hidden;
    const float4* whp = (const float4*)w_hidden;
    const int4*   sop = (const int4*)src_out;
    const float4* wop = (const float4*)w_out;

    // ---- Prefetch layer-0 weights (in flight under x-staging + barrier).
    SW A, B;
    load_sw(shp + (n0 << 2), whp + (n0 << 2), A);
    load_sw(shp + (n1 << 2), whp + (n1 << 2), B);

    // ---- Stage x: fp32 -> fp16 half-rows, 2 node passes. Coalesced.
    #pragma unroll
    for (int p = 0; p < 2; ++p) {
        const int n = (p << 9) + pr;
        h8 hv;
        #pragma unroll
        for (int j = 0; j < 8; ++j)
            hv[j] = (_Float16)x[(size_t)(bb + j) * W_NODES + n];
        *(h8*)(bufA + n * ROW_H + hfo) = hv;   // 8 lanes/quad-group: clean
    }
    __syncthreads();

    _Float16* rd = bufA;
    _Float16* wr = bufB;

#define LDV(S, i) (*(const h8*)(rd + ((S[i] << 4) + hfo)))
#define FMA8(acc, g, w)                                   \
    do {                                                  \
        const float _w = (w);                             \
        _Pragma("unroll")                                 \
        for (int j = 0; j < 8; ++j)                       \
            acc[j] = fmaf((float)(g)[j], _w, acc[j]);     \
    } while (0)

    #pragma unroll 1
    for (int l = 0; l < LAYERS; ++l) {
        int   si0[16], si1[16];
        float wi0[16], wi1[16];
        unpack_sw(A, si0, wi0);
        unpack_sw(B, si1, wi1);

        const bool last = (l == LAYERS - 1);
        const int  rn0 = ((l + 1) << 10) + n0;
        const int  rn1 = ((l + 1) << 10) + n1;
        const int4*   spA = last ? sop + (n0 << 2) : shp + (rn0 << 2);
        const float4* wpA = last ? wop + (n0 << 2) : whp + (rn0 << 2);
        const int4*   spB = last ? sop + (n1 << 2) : shp + (rn1 << 2);
        const float4* wpB = last ? wop + (n1 << 2) : whp + (rn1 << 2);

        float acc0[8], acc1[8];
        #pragma unroll
        for (int j = 0; j < 8; ++j) acc0[j] = 0.0f;

        // ---- pass 0 gather: rolling 8-deep.
        h8 g0 = LDV(si0, 0);  h8 g1 = LDV(si0, 1);
        h8 g2 = LDV(si0, 2);  h8 g3 = LDV(si0, 3);
        h8 g4 = LDV(si0, 4);  h8 g5 = LDV(si0, 5);
        h8 g6 = LDV(si0, 6);  h8 g7 = LDV(si0, 7);

        FMA8(acc0, g0, wi0[0]);  FMA8(acc0, g1, wi0[1]);
        g0 = LDV(si0, 8);        g1 = LDV(si0, 9);
        FMA8(acc0, g2, wi0[2]);  FMA8(acc0, g3, wi0[3]);
        g2 = LDV(si0, 10);       g3 = LDV(si0, 11);
        FMA8(acc0, g4, wi0[4]);  FMA8(acc0, g5, wi0[5]);
        g4 = LDV(si0, 12);       g5 = LDV(si0, 13);
        FMA8(acc0, g6, wi0[6]);  FMA8(acc0, g7, wi0[7]);
        g6 = LDV(si0, 14);       g7 = LDV(si0, 15);

        // ---- pass-0 tail FMAs; issue pass-1's first 8 loads so the LDS
        // pipe stays fed through the tanh-0 tail.
        h8 h0 = LDV(si1, 0);     h8 h1 = LDV(si1, 1);
        FMA8(acc0, g0, wi0[8]);  FMA8(acc0, g1, wi0[9]);
        h8 h2 = LDV(si1, 2);     h8 h3 = LDV(si1, 3);
        FMA8(acc0, g2, wi0[10]); FMA8(acc0, g3, wi0[11]);
        h8 h4 = LDV(si1, 4);     h8 h5 = LDV(si1, 5);
        FMA8(acc0, g4, wi0[12]); FMA8(acc0, g5, wi0[13]);
        h8 h6 = LDV(si1, 6);     h8 h7 = LDV(si1, 7);
        FMA8(acc0, g6, wi0[14]); FMA8(acc0, g7, wi0[15]);

        // tanh + write pass 0 (pass-1 loads in flight).
        {
            h8 hv;
            #pragma unroll
            for (int j = 0; j < 8; ++j) hv[j] = (_Float16)fast_tanh(acc0[j]);
            *(h8*)(wr + n0 * ROW_H + hfo) = hv;
        }

        // next-layer pass-0 weights: one full compute-pass ahead of use.
        load_sw(spA, wpA, A);

        #pragma unroll
        for (int j = 0; j < 8; ++j) acc1[j] = 0.0f;

        // ---- pass 1: first 8 already in flight, keep rolling.
        FMA8(acc1, h0, wi1[0]);  FMA8(acc1, h1, wi1[1]);
        h0 = LDV(si1, 8);        h1 = LDV(si1, 9);
        FMA8(acc1, h2, wi1[2]);  FMA8(acc1, h3, wi1[3]);
        h2 = LDV(si1, 10);       h3 = LDV(si1, 11);
        FMA8(acc1, h4, wi1[4]);  FMA8(acc1, h5, wi1[5]);
        h4 = LDV(si1, 12);       h5 = LDV(si1, 13);
        FMA8(acc1, h6, wi1[6]);  FMA8(acc1, h7, wi1[7]);
        h6 = LDV(si1, 14);       h7 = LDV(si1, 15);

        FMA8(acc1, h0, wi1[8]);  FMA8(acc1, h1, wi1[9]);
        FMA8(acc1, h2, wi1[10]); FMA8(acc1, h3, wi1[11]);
        FMA8(acc1, h4, wi1[12]); FMA8(acc1, h5, wi1[13]);
        FMA8(acc1, h6, wi1[14]); FMA8(acc1, h7, wi1[15]);

        // next-layer pass-1 weights (needed only after next pass-0).
        load_sw(spB, wpB, B);

        // tanh + write pass 1.
        {
            h8 hv;
            #pragma unroll
            for (int j = 0; j < 8; ++j) hv[j] = (_Float16)fast_tanh(acc1[j]);
            *(h8*)(wr + n1 * ROW_H + hfo) = hv;
        }

        __syncthreads();
        _Float16* tmp = rd; rd = wr; wr = tmp;
    }

    // ---- Output layer: identity activation, fused passes, fp32 stores.
    {
        int   si0[16], si1[16];
        float wi0[16], wi1[16];
        unpack_sw(A, si0, wi0);
        unpack_sw(B, si1, wi1);

        float acc0[8], acc1[8];
        #pragma unroll
        for (int j = 0; j < 8; ++j) acc0[j] = 0.0f;

        h8 g0 = LDV(si0, 0);  h8 g1 = LDV(si0, 1);
        h8 g2 = LDV(si0, 2);  h8 g3 = LDV(si0, 3);
        h8 g4 = LDV(si0, 4);  h8 g5 = LDV(si0, 5);
        h8 g6 = LDV(si0, 6);  h8 g7 = LDV(si0, 7);

        FMA8(acc0, g0, wi0[0]);  FMA8(acc0, g1, wi0[1]);
        g0 = LDV(si0, 8);        g1 = LDV(si0, 9);
        FMA8(acc0, g2, wi0[2]);  FMA8(acc0, g3, wi0[3]);
        g2 = LDV(si0, 10);       g3 = LDV(si0, 11);
        FMA8(acc0, g4, wi0[4]);  FMA8(acc0, g5, wi0[5]);
        g4 = LDV(si0, 12);       g5 = LDV(si0, 13);
        FMA8(acc0, g6, wi0[6]);  FMA8(acc0, g7, wi0[7]);
        g6 = LDV(si0, 14);       g7 = LDV(si0, 15);

        h8 h0 = LDV(si1, 0);     h8 h1 = LDV(si1, 1);
        FMA8(acc0, g0, wi0[8]);  FMA8(acc0, g1, wi0[9]);
        h8 h2 = LDV(si1, 2);     h8 h3 = LDV(si1, 3);
        FMA8(acc0, g2, wi0[10]); FMA8(acc0, g3, wi0[11]);
        h8 h4 = LDV(si1, 4);     h8 h5 = LDV(si1, 5);
        FMA8(acc0, g4, wi0[12]); FMA8(acc0, g5, wi0[13]);
        h8 h6 = LDV(si1, 6);     h8 h7 = LDV(si1, 7);
        FMA8(acc0, g6, wi0[14]); FMA8(acc0, g7, wi0[15]);

        // stores for pass 0 (pass-1 loads in flight); coalesced per j.
        #pragma unroll
        for (int j = 0; j < 8; ++j)
            out[(size_t)(bb + j) * W_NODES + n0] = acc0[j];

        #pragma unroll
        for (int j = 0; j < 8; ++j) acc1[j] = 0.0f;

        FMA8(acc1, h0, wi1[0]);  FMA8(acc1, h1, wi1[1]);
        h0 = LDV(si1, 8);        h1 = LDV(si1, 9);
        FMA8(acc1, h2, wi1[2]);  FMA8(acc1, h3, wi1[3]);
        h2 = LDV(si1, 10);       h3 = LDV(si1, 11);
        FMA8(acc1, h4, wi1[4]);  FMA8(acc1, h5, wi1[5]);
        h4 = LDV(si1, 12);       h5 = LDV(si1, 13);
        FMA8(acc1, h6, wi1[6]);  FMA8(acc1, h7, wi1[7]);
        h6 = LDV(si1, 14);       h7 = LDV(si1, 15);

        FMA8(acc1, h0, wi1[8]);  FMA8(acc1, h1, wi1[9]);
        FMA8(acc1, h2, wi1[10]); FMA8(acc1, h3, wi1[11]);
        FMA8(acc1, h4, wi1[12]); FMA8(acc1, h5, wi1[13]);
        FMA8(acc1, h6, wi1[14]); FMA8(acc1, h7, wi1[15]);

        #pragma unroll
        for (int j = 0; j < 8; ++j)
            out[(size_t)(bb + j) * W_NODES + n1] = acc1[j];
    }

#undef LDV
#undef FMA8
}

extern "C" void kernel_launch(void* const* d_in, const int* in_sizes, int n_in,
                              void* d_out, int out_size, void* d_ws, size_t ws_size,
                              hipStream_t stream) {
    const float* x  = (const float*)d_in[0];
    const int*   sh = (const int*)  d_in[1];
    const float* wh = (const float*)d_in[2];
    const int*   so = (const int*)  d_in[3];
    const float* wo = (const float*)d_in[4];
    float* out = (float*)d_out;

    const int shmem = 2 * BUF_H * (int)sizeof(_Float16);   // 65536 B
    hipFuncSetAttribute(reinterpret_cast<const void*>(genome_net),
                        hipFuncAttributeMaxDynamicSharedMemorySize, shmem);

    genome_net<<<dim3(4096 / TB), dim3(1024), shmem, stream>>>(
        x, sh, wh, so, wo, out);
}